// Round 5
// baseline (364.733 us; speedup 1.0000x reference)
//
#include <hip/hip_runtime.h>
#include <cstdint>

#define B 32
#define L 512
#define T 2048
#define M 80
#define KDIM 160

#define NEG_INF (-1e30f)
#define LOG_2PI 1.8378770664093453f

// robust to harness passing lengths as int32 or int64 (values are small positive;
// if int64, word[1] == high word of elem0 == 0; if int32, word[1] in [64,2048] != 0)
__device__ __forceinline__ int get_len(const int* __restrict__ p, int b) {
  return (p[1] == 0) ? p[2 * b] : p[b];
}

// ---------------- prep: Wmat[b][k][l], bias[b][l] ----------------
__global__ __launch_bounds__(256) void prep_kernel(const float* __restrict__ mu_sigma,
                                                   float* __restrict__ Wmat,
                                                   float* __restrict__ biasv) {
  int gid = blockIdx.x * 256 + threadIdx.x;  // b*L + l
  if (gid >= B * L) return;
  int b = gid >> 9;
  int l = gid & (L - 1);
  const float* row = mu_sigma + (size_t)gid * (2 * M);
  float* wb = Wmat + (size_t)b * KDIM * L + l;
  float acc_a = 0.f, acc_ls = 0.f;
#pragma unroll 4
  for (int m = 0; m < M; ++m) {
    float mu = row[m];
    float ls = row[M + m];
    float iv = expf(-2.f * ls);
    acc_a += mu * mu * iv;
    acc_ls += ls;
    wb[(size_t)m * L] = -0.5f * iv;
    wb[(size_t)(M + m) * L] = mu * iv;
  }
  biasv[gid] = -0.5f * acc_a - (0.5f * (float)M * LOG_2PI + 0.5f * acc_ls);
}

// ---------------- gemm: logpT[b][t][l] = bias[l] + sum_k X[k][t]*W[k][l] ----------------
#define LT 64
#define LL 64
#define KC 40
__global__ __launch_bounds__(256) void gemm_logp(const float* __restrict__ x,
                                                 const float* __restrict__ Wmat,
                                                 const float* __restrict__ biasv,
                                                 const int* __restrict__ mel_len,
                                                 const int* __restrict__ text_len,
                                                 float* __restrict__ logpT,
                                                 int t_begin, int tc) {
  int b = blockIdx.z;
  int t0 = t_begin + blockIdx.x * LT;
  int l0 = blockIdx.y * LL;
  if (t0 >= get_len(mel_len, b)) return;
  if (l0 >= get_len(text_len, b)) return;

  __shared__ float Xs[KC][LT];
  __shared__ float Ws[KC][LL];
  int tid = threadIdx.x;
  int tx = tid & 15;   // t quad
  int ly = tid >> 4;   // l quad

  float acc[4][4];
#pragma unroll
  for (int i = 0; i < 4; ++i)
#pragma unroll
    for (int j = 0; j < 4; ++j) acc[i][j] = 0.f;

  for (int kc = 0; kc < KDIM; kc += KC) {
    bool sq = (kc < M);
#pragma unroll
    for (int p = 0; p < (KC * LT) / 256; ++p) {  // 10 passes
      int idx = p * 256 + tid;
      int kk = idx >> 6;
      int cc = idx & 63;
      int k = kc + kk;
      int m = sq ? k : (k - M);
      float xv = x[((size_t)b * M + m) * T + t0 + cc];
      Xs[kk][cc] = sq ? xv * xv : xv;
      Ws[kk][cc] = Wmat[((size_t)b * KDIM + k) * L + l0 + cc];
    }
    __syncthreads();
#pragma unroll 8
    for (int k = 0; k < KC; ++k) {
      float xa[4], wa[4];
#pragma unroll
      for (int i = 0; i < 4; ++i) xa[i] = Xs[k][tx * 4 + i];
#pragma unroll
      for (int j = 0; j < 4; ++j) wa[j] = Ws[k][ly * 4 + j];
#pragma unroll
      for (int i = 0; i < 4; ++i)
#pragma unroll
        for (int j = 0; j < 4; ++j) acc[i][j] += xa[i] * wa[j];
    }
    __syncthreads();
  }

  float bb[4];
#pragma unroll
  for (int j = 0; j < 4; ++j) bb[j] = biasv[b * L + l0 + ly * 4 + j];
#pragma unroll
  for (int i = 0; i < 4; ++i) {
    int t = t0 + tx * 4 + i;
    float4 v;
    v.x = acc[i][0] + bb[0];
    v.y = acc[i][1] + bb[1];
    v.z = acc[i][2] + bb[2];
    v.w = acc[i][3] + bb[3];
    *(float4*)(logpT + ((size_t)b * tc + (t - t_begin)) * L + l0 + ly * 4) = v;
  }
}

// ---------------- scan: one wave per batch, max-plus recursion ----------------
// Lane i owns l in [4i,4i+4) (c0) and [256+4i,256+4i+4) (c1): both row reads are
// lane-stride-16B ds_read_b128 -> bank-conflict-free. Neighbor values via DPP:
// wave_shr:1 for c0 (lane0 <- NEG_INF), wave_ror:1 of a lane63-select for c1.
#define SB 8
#define NBUF 4
__device__ __forceinline__ float dpp_shr1_neginf(float x) {
  int r = __builtin_amdgcn_update_dpp(__float_as_int(NEG_INF), __float_as_int(x),
                                      0x138, 0xf, 0xf, false);  // wave_shr:1
  return __int_as_float(r);
}
__device__ __forceinline__ float dpp_ror1(float x) {
  int r = __builtin_amdgcn_update_dpp(0, __float_as_int(x),
                                      0x13C, 0xf, 0xf, false);  // wave_ror:1
  return __int_as_float(r);
}

__global__ __launch_bounds__(64) void scan_kernel(const float* __restrict__ logpT,
                                                  const int* __restrict__ mel_len,
                                                  const int* __restrict__ text_len,
                                                  float* __restrict__ carry_ws,
                                                  float* __restrict__ la_ws,
                                                  int t_begin, int tc) {
  __shared__ float lds[NBUF][SB][L];  // 64 KB
  int b = blockIdx.x;
  int lane = threadIdx.x;
  int ml = get_len(mel_len, b);
  int tl = get_len(text_len, b);
  const float* base0 = logpT + (size_t)b * tc * L;
  float* cws = carry_ws + b * L;
  bool is63 = (lane == 63);

  float c0[4], c1[4];
  int tstart;
  if (t_begin == 0) {
#pragma unroll
    for (int j = 0; j < 4; ++j) { c0[j] = NEG_INF; c1[j] = NEG_INF; }
    if (lane == 0) c0[0] = base0[0];  // logp[b,0,0] at l=0
    tstart = 1;
  } else {
    float4 v0 = *(const float4*)(cws + 4 * lane);
    float4 v1 = *(const float4*)(cws + 256 + 4 * lane);
    c0[0] = v0.x; c0[1] = v0.y; c0[2] = v0.z; c0[3] = v0.w;
    c1[0] = v1.x; c1[1] = v1.y; c1[2] = v1.z; c1[3] = v1.w;
    tstart = t_begin;
  }

  int tstop = min(t_begin + tc, ml);

  auto step = [&](float4 l0, float4 l1) {
    float pb0 = dpp_shr1_neginf(c0[3]);        // lane i-1's c0[3] (old)
    float merged = is63 ? c0[3] : c1[3];
    float pb1 = dpp_ror1(merged);              // lane i-1's c1[3]; lane0 <- lane63 c0[3]
    c1[3] = fmaxf(c1[3], c1[2]) + l1.w;
    c1[2] = fmaxf(c1[2], c1[1]) + l1.z;
    c1[1] = fmaxf(c1[1], c1[0]) + l1.y;
    c1[0] = fmaxf(c1[0], pb1) + l1.x;
    c0[3] = fmaxf(c0[3], c0[2]) + l0.w;
    c0[2] = fmaxf(c0[2], c0[1]) + l0.z;
    c0[1] = fmaxf(c0[1], c0[0]) + l0.y;
    c0[0] = fmaxf(c0[0], pb0) + l0.x;
  };

  int nb = (tstop > t_begin) ? ((tstop - t_begin + SB - 1) / SB) : 0;
  if (nb > 0) {
    auto stage = [&](int i) {
      int tb = t_begin + i * SB;
      if (tb >= tstop) return;
      const float* src = base0 + (size_t)(tb - t_begin) * L;
      float* dst = &lds[i & (NBUF - 1)][0][0];
#pragma unroll
      for (int u = 0; u < (SB * L) / 256; ++u)  // 16 x 1KB
        __builtin_amdgcn_global_load_lds(
            (const __attribute__((address_space(1))) void*)(src + u * 256 + lane * 4),
            (__attribute__((address_space(3))) void*)(dst + u * 256), 16, 0, 0);
    };
    stage(0); stage(1); stage(2);
    for (int i = 0; i < nb; ++i) {
      stage(i + 3);
      int rem = nb - 1 - i;  // stages actually issued after i
      if (rem >= 3)      asm volatile("s_waitcnt vmcnt(48)" ::: "memory");
      else if (rem == 2) asm volatile("s_waitcnt vmcnt(32)" ::: "memory");
      else if (rem == 1) asm volatile("s_waitcnt vmcnt(16)" ::: "memory");
      else               asm volatile("s_waitcnt vmcnt(0)"  ::: "memory");
      int tb = t_begin + i * SB;
      int e = min(tb + SB, tstop);
      int rb = max(tb, tstart);
      const float* rowp = &lds[i & (NBUF - 1)][0][4 * lane];  // block0 base
      if (rb == tb && e == tb + SB) {
#pragma unroll
        for (int r = 0; r < SB; ++r) {
          float4 l0 = *(const float4*)(rowp + r * L);
          float4 l1 = *(const float4*)(rowp + r * L + 256);
          step(l0, l1);
        }
      } else {
        for (int t = rb; t < e; ++t) {
          float4 l0 = *(const float4*)(rowp + (size_t)(t - tb) * L);
          float4 l1 = *(const float4*)(rowp + (size_t)(t - tb) * L + 256);
          step(l0, l1);
        }
      }
    }
  }

  // persist carry for next chunk (natural-l layout)
  *(float4*)(cws + 4 * lane) = make_float4(c0[0], c0[1], c0[2], c0[3]);
  *(float4*)(cws + 256 + 4 * lane) = make_float4(c1[0], c1[1], c1[2], c1[3]);

  if (t_begin + tc >= T) {  // last chunk: la[b] = alpha[ml-1][tl-1]
    int li = tl - 1;
    int sub = li & 3;
    float v0 = (sub == 0) ? c0[0] : (sub == 1) ? c0[1] : (sub == 2) ? c0[2] : c0[3];
    float v1 = (sub == 0) ? c1[0] : (sub == 1) ? c1[1] : (sub == 2) ? c1[2] : c1[3];
    float v = (li < 256) ? v0 : v1;
    int sl = (li < 256) ? (li >> 2) : ((li - 256) >> 2);
    float lav = __shfl(v, sl);
    if (lane == 0) la_ws[b] = lav;
  }
}

__global__ __launch_bounds__(64) void reduce_kernel(const float* __restrict__ la_ws,
                                                    float* __restrict__ out) {
  int lane = threadIdx.x;
  float v = (lane < B) ? la_ws[lane] : 0.f;
#pragma unroll
  for (int s = 32; s > 0; s >>= 1) v += __shfl_down(v, s);
  if (lane == 0) out[0] = -v * (1.0f / (float)B);
}

extern "C" void kernel_launch(void* const* d_in, const int* in_sizes, int n_in,
                              void* d_out, int out_size, void* d_ws, size_t ws_size,
                              hipStream_t stream) {
  const float* mu_sigma = (const float*)d_in[0];
  const float* melspec  = (const float*)d_in[1];
  const int*   text_len = (const int*)d_in[2];
  const int*   mel_len  = (const int*)d_in[3];
  float* out = (float*)d_out;

  char* ws = (char*)d_ws;
  size_t off = 0;
  float* Wmat = (float*)(ws + off);      off += (size_t)B * KDIM * L * 4;  // 10.5 MB
  float* biasv = (float*)(ws + off);     off += (size_t)B * L * 4;
  float* carry_ws = (float*)(ws + off);  off += (size_t)B * L * 4;
  float* la_ws = (float*)(ws + off);     off += 256;
  float* logpT = (float*)(ws + off);
  size_t avail = (ws_size > off) ? (ws_size - off) : 0;
  size_t per_t = (size_t)B * L * 4;  // bytes per t-slice across all b
  long long tcl = (long long)(avail / per_t);
  int Tc = (tcl > T) ? T : (int)tcl;
  Tc &= ~63;
  if (Tc < 64) return;  // insufficient workspace (not expected)

  prep_kernel<<<dim3((B * L + 255) / 256), 256, 0, stream>>>(mu_sigma, Wmat, biasv);

  for (int t_begin = 0; t_begin < T; t_begin += Tc) {
    int tc = (T - t_begin < Tc) ? (T - t_begin) : Tc;
    dim3 grid(tc / LT, L / LL, B);
    gemm_logp<<<grid, 256, 0, stream>>>(melspec, Wmat, biasv, mel_len, text_len,
                                        logpT, t_begin, tc);
    scan_kernel<<<dim3(B), 64, 0, stream>>>(logpT, mel_len, text_len, carry_ws,
                                            la_ws, t_begin, tc);
  }
  reduce_kernel<<<1, 64, 0, stream>>>(la_ws, out);
}

// Round 6
// 280.860 us; speedup vs baseline: 1.2986x; 1.2986x over previous
//
#include <hip/hip_runtime.h>
#include <cstdint>

#define B 32
#define L 512
#define T 2048
#define M 80
#define KDIM 160

#define NEG_INF (-1e30f)
#define LOG_2PI 1.8378770664093453f

typedef float f32x4 __attribute__((ext_vector_type(4)));

// robust to harness passing lengths as int32 or int64 (values are small positive;
// if int64, word[1] == high word of elem0 == 0; if int32, word[1] in [64,2048] != 0)
__device__ __forceinline__ int get_len(const int* __restrict__ p, int b) {
  return (p[1] == 0) ? p[2 * b] : p[b];
}

// ---------------- prep: Wmat[b][k][l], bias[b][l] ----------------
__global__ __launch_bounds__(256) void prep_kernel(const float* __restrict__ mu_sigma,
                                                   float* __restrict__ Wmat,
                                                   float* __restrict__ biasv) {
  int gid = blockIdx.x * 256 + threadIdx.x;  // b*L + l
  if (gid >= B * L) return;
  int b = gid >> 9;
  int l = gid & (L - 1);
  const float* row = mu_sigma + (size_t)gid * (2 * M);
  float* wb = Wmat + (size_t)b * KDIM * L + l;
  float acc_a = 0.f, acc_ls = 0.f;
#pragma unroll 4
  for (int m = 0; m < M; ++m) {
    float mu = row[m];
    float ls = row[M + m];
    float iv = expf(-2.f * ls);
    acc_a += mu * mu * iv;
    acc_ls += ls;
    wb[(size_t)m * L] = -0.5f * iv;
    wb[(size_t)(M + m) * L] = mu * iv;
  }
  biasv[gid] = -0.5f * acc_a - (0.5f * (float)M * LOG_2PI + 0.5f * acc_ls);
}

// ---------------- gemm: logpT[b][t][l] = bias[l] + sum_k X[k][t]*W[k][l] ----------------
#define LT 64
#define LL 64
#define KC 40
__global__ __launch_bounds__(256) void gemm_logp(const float* __restrict__ x,
                                                 const float* __restrict__ Wmat,
                                                 const float* __restrict__ biasv,
                                                 const int* __restrict__ mel_len,
                                                 const int* __restrict__ text_len,
                                                 float* __restrict__ logpT,
                                                 int t_begin, int tc) {
  int b = blockIdx.z;
  int t0 = t_begin + blockIdx.x * LT;
  int l0 = blockIdx.y * LL;
  if (t0 >= get_len(mel_len, b)) return;
  if (l0 >= get_len(text_len, b)) return;

  __shared__ float Xs[KC][LT];
  __shared__ float Ws[KC][LL];
  int tid = threadIdx.x;
  int tx = tid & 15;   // t quad
  int ly = tid >> 4;   // l quad

  float acc[4][4];
#pragma unroll
  for (int i = 0; i < 4; ++i)
#pragma unroll
    for (int j = 0; j < 4; ++j) acc[i][j] = 0.f;

  for (int kc = 0; kc < KDIM; kc += KC) {
    bool sq = (kc < M);
#pragma unroll
    for (int p = 0; p < (KC * LT) / 256; ++p) {  // 10 passes
      int idx = p * 256 + tid;
      int kk = idx >> 6;
      int cc = idx & 63;
      int k = kc + kk;
      int m = sq ? k : (k - M);
      float xv = x[((size_t)b * M + m) * T + t0 + cc];
      Xs[kk][cc] = sq ? xv * xv : xv;
      Ws[kk][cc] = Wmat[((size_t)b * KDIM + k) * L + l0 + cc];
    }
    __syncthreads();
#pragma unroll 8
    for (int k = 0; k < KC; ++k) {
      float xa[4], wa[4];
#pragma unroll
      for (int i = 0; i < 4; ++i) xa[i] = Xs[k][tx * 4 + i];
#pragma unroll
      for (int j = 0; j < 4; ++j) wa[j] = Ws[k][ly * 4 + j];
#pragma unroll
      for (int i = 0; i < 4; ++i)
#pragma unroll
        for (int j = 0; j < 4; ++j) acc[i][j] += xa[i] * wa[j];
    }
    __syncthreads();
  }

  float bb[4];
#pragma unroll
  for (int j = 0; j < 4; ++j) bb[j] = biasv[b * L + l0 + ly * 4 + j];
#pragma unroll
  for (int i = 0; i < 4; ++i) {
    int t = t0 + tx * 4 + i;
    float4 v;
    v.x = acc[i][0] + bb[0];
    v.y = acc[i][1] + bb[1];
    v.z = acc[i][2] + bb[2];
    v.w = acc[i][3] + bb[3];
    *(float4*)(logpT + ((size_t)b * tc + (t - t_begin)) * L + l0 + ly * 4) = v;
  }
}

// ---------------- scan: one wave per batch, max-plus recursion ----------------
// Lane i owns l in [4i,4i+4) (c0) and [256+4i,256+4i+4) (c1); conflict-free
// 16B-stride ds_read_b128. Per 8-row block: hand-hoisted inline-asm ds_reads
// into 16 named f32x4 regs + counted lgkmcnt per step (latency paid once per
// block, not per read). Neighbor values via DPP (pure VALU).
#define SB 8
#define NBUF 4

#define DS_READ_B128(dst, addr, imm) \
  asm volatile("ds_read_b128 %0, %1 offset:" #imm : "=v"(dst) : "v"(addr))
#define LGKM(n)                                             \
  do {                                                      \
    asm volatile("s_waitcnt lgkmcnt(" #n ")" ::: "memory"); \
    __builtin_amdgcn_sched_barrier(0);                      \
  } while (0)

__device__ __forceinline__ float dpp_shr1_neginf(float x) {
  int r = __builtin_amdgcn_update_dpp(__float_as_int(NEG_INF), __float_as_int(x),
                                      0x138, 0xf, 0xf, false);  // wave_shr:1
  return __int_as_float(r);
}
__device__ __forceinline__ float dpp_ror1(float x) {
  int r = __builtin_amdgcn_update_dpp(0, __float_as_int(x),
                                      0x13C, 0xf, 0xf, false);  // wave_ror:1
  return __int_as_float(r);
}

__global__ __launch_bounds__(64) void scan_kernel(const float* __restrict__ logpT,
                                                  const int* __restrict__ mel_len,
                                                  const int* __restrict__ text_len,
                                                  float* __restrict__ carry_ws,
                                                  float* __restrict__ la_ws,
                                                  int t_begin, int tc) {
  __shared__ float lds[NBUF][SB][L];  // 64 KB
  int b = blockIdx.x;
  int lane = threadIdx.x;
  int ml = get_len(mel_len, b);
  int tl = get_len(text_len, b);
  const float* base0 = logpT + (size_t)b * tc * L;
  float* cws = carry_ws + b * L;
  bool is63 = (lane == 63);

  float c0[4], c1[4];
  int tstart;
  if (t_begin == 0) {
#pragma unroll
    for (int j = 0; j < 4; ++j) { c0[j] = NEG_INF; c1[j] = NEG_INF; }
    if (lane == 0) c0[0] = base0[0];  // logp[b,0,0] at l=0
    tstart = 1;
  } else {
    float4 v0 = *(const float4*)(cws + 4 * lane);
    float4 v1 = *(const float4*)(cws + 256 + 4 * lane);
    c0[0] = v0.x; c0[1] = v0.y; c0[2] = v0.z; c0[3] = v0.w;
    c1[0] = v1.x; c1[1] = v1.y; c1[2] = v1.z; c1[3] = v1.w;
    tstart = t_begin;
  }

  int tstop = min(t_begin + tc, ml);

  auto step = [&](f32x4 l0, f32x4 l1) {
    float pb0 = dpp_shr1_neginf(c0[3]);        // lane i-1's c0[3] (old)
    float merged = is63 ? c0[3] : c1[3];
    float pb1 = dpp_ror1(merged);              // lane i-1's c1[3]; lane0 <- lane63 c0[3]
    c1[3] = fmaxf(c1[3], c1[2]) + l1[3];
    c1[2] = fmaxf(c1[2], c1[1]) + l1[2];
    c1[1] = fmaxf(c1[1], c1[0]) + l1[1];
    c1[0] = fmaxf(c1[0], pb1) + l1[0];
    c0[3] = fmaxf(c0[3], c0[2]) + l0[3];
    c0[2] = fmaxf(c0[2], c0[1]) + l0[2];
    c0[1] = fmaxf(c0[1], c0[0]) + l0[1];
    c0[0] = fmaxf(c0[0], pb0) + l0[0];
  };

  int nb = (tstop > t_begin) ? ((tstop - t_begin + SB - 1) / SB) : 0;
  if (nb > 0) {
    auto stage = [&](int i) {
      int tb = t_begin + i * SB;
      if (tb >= tstop) return;
      const float* src = base0 + (size_t)(tb - t_begin) * L;
      float* dst = &lds[i & (NBUF - 1)][0][0];
#pragma unroll
      for (int u = 0; u < (SB * L) / 256; ++u)  // 16 x 1KB
        __builtin_amdgcn_global_load_lds(
            (const __attribute__((address_space(1))) void*)(src + u * 256 + lane * 4),
            (__attribute__((address_space(3))) void*)(dst + u * 256), 16, 0, 0);
    };
    stage(0); stage(1); stage(2);
    for (int i = 0; i < nb; ++i) {
      stage(i + 3);
      int rem = nb - 1 - i;  // stages actually issued after i
      if (rem >= 3)      asm volatile("s_waitcnt vmcnt(48)" ::: "memory");
      else if (rem == 2) asm volatile("s_waitcnt vmcnt(32)" ::: "memory");
      else if (rem == 1) asm volatile("s_waitcnt vmcnt(16)" ::: "memory");
      else               asm volatile("s_waitcnt vmcnt(0)"  ::: "memory");
      int tb = t_begin + i * SB;
      int e = min(tb + SB, tstop);
      int rb = max(tb, tstart);
      // LDS byte address of this block's lane base (addrspace(3) => 0-based)
      uint32_t basea =
          (uint32_t)(uintptr_t)(__attribute__((address_space(3)))
                                float*)(&lds[i & (NBUF - 1)][0][0]) +
          16u * (uint32_t)lane;
      if (rb == tb && e == tb + SB) {
        f32x4 r0a, r0b, r1a, r1b, r2a, r2b, r3a, r3b;
        f32x4 r4a, r4b, r5a, r5b, r6a, r6b, r7a, r7b;
        DS_READ_B128(r0a, basea, 0);
        DS_READ_B128(r0b, basea, 1024);
        DS_READ_B128(r1a, basea, 2048);
        DS_READ_B128(r1b, basea, 3072);
        DS_READ_B128(r2a, basea, 4096);
        DS_READ_B128(r2b, basea, 5120);
        DS_READ_B128(r3a, basea, 6144);
        DS_READ_B128(r3b, basea, 7168);
        DS_READ_B128(r4a, basea, 8192);
        DS_READ_B128(r4b, basea, 9216);
        DS_READ_B128(r5a, basea, 10240);
        DS_READ_B128(r5b, basea, 11264);
        DS_READ_B128(r6a, basea, 12288);
        DS_READ_B128(r6b, basea, 13312);
        DS_READ_B128(r7a, basea, 14336);
        DS_READ_B128(r7b, basea, 15360);
        LGKM(14); step(r0a, r0b);
        LGKM(12); step(r1a, r1b);
        LGKM(10); step(r2a, r2b);
        LGKM(8);  step(r3a, r3b);
        LGKM(6);  step(r4a, r4b);
        LGKM(4);  step(r5a, r5b);
        LGKM(2);  step(r6a, r6b);
        LGKM(0);  step(r7a, r7b);
      } else {
        const float* rowp = &lds[i & (NBUF - 1)][0][4 * lane];
        for (int t = rb; t < e; ++t) {
          float4 a = *(const float4*)(rowp + (size_t)(t - tb) * L);
          float4 d = *(const float4*)(rowp + (size_t)(t - tb) * L + 256);
          f32x4 l0 = {a.x, a.y, a.z, a.w};
          f32x4 l1 = {d.x, d.y, d.z, d.w};
          step(l0, l1);
        }
      }
    }
  }

  // persist carry for next chunk (natural-l layout)
  *(float4*)(cws + 4 * lane) = make_float4(c0[0], c0[1], c0[2], c0[3]);
  *(float4*)(cws + 256 + 4 * lane) = make_float4(c1[0], c1[1], c1[2], c1[3]);

  if (t_begin + tc >= T) {  // last chunk: la[b] = alpha[ml-1][tl-1]
    int li = tl - 1;
    int sub = li & 3;
    float v0 = (sub == 0) ? c0[0] : (sub == 1) ? c0[1] : (sub == 2) ? c0[2] : c0[3];
    float v1 = (sub == 0) ? c1[0] : (sub == 1) ? c1[1] : (sub == 2) ? c1[2] : c1[3];
    float v = (li < 256) ? v0 : v1;
    int sl = (li < 256) ? (li >> 2) : ((li - 256) >> 2);
    float lav = __shfl(v, sl);
    if (lane == 0) la_ws[b] = lav;
  }
}

__global__ __launch_bounds__(64) void reduce_kernel(const float* __restrict__ la_ws,
                                                    float* __restrict__ out) {
  int lane = threadIdx.x;
  float v = (lane < B) ? la_ws[lane] : 0.f;
#pragma unroll
  for (int s = 32; s > 0; s >>= 1) v += __shfl_down(v, s);
  if (lane == 0) out[0] = -v * (1.0f / (float)B);
}

extern "C" void kernel_launch(void* const* d_in, const int* in_sizes, int n_in,
                              void* d_out, int out_size, void* d_ws, size_t ws_size,
                              hipStream_t stream) {
  const float* mu_sigma = (const float*)d_in[0];
  const float* melspec  = (const float*)d_in[1];
  const int*   text_len = (const int*)d_in[2];
  const int*   mel_len  = (const int*)d_in[3];
  float* out = (float*)d_out;

  char* ws = (char*)d_ws;
  size_t off = 0;
  float* Wmat = (float*)(ws + off);      off += (size_t)B * KDIM * L * 4;  // 10.5 MB
  float* biasv = (float*)(ws + off);     off += (size_t)B * L * 4;
  float* carry_ws = (float*)(ws + off);  off += (size_t)B * L * 4;
  float* la_ws = (float*)(ws + off);     off += 256;
  float* logpT = (float*)(ws + off);
  size_t avail = (ws_size > off) ? (ws_size - off) : 0;
  size_t per_t = (size_t)B * L * 4;  // bytes per t-slice across all b
  long long tcl = (long long)(avail / per_t);
  int Tc = (tcl > T) ? T : (int)tcl;
  Tc &= ~63;
  if (Tc < 64) return;  // insufficient workspace (not expected)

  prep_kernel<<<dim3((B * L + 255) / 256), 256, 0, stream>>>(mu_sigma, Wmat, biasv);

  for (int t_begin = 0; t_begin < T; t_begin += Tc) {
    int tc = (T - t_begin < Tc) ? (T - t_begin) : Tc;
    dim3 grid(tc / LT, L / LL, B);
    gemm_logp<<<grid, 256, 0, stream>>>(melspec, Wmat, biasv, mel_len, text_len,
                                        logpT, t_begin, tc);
    scan_kernel<<<dim3(B), 64, 0, stream>>>(logpT, mel_len, text_len, carry_ws,
                                            la_ws, t_begin, tc);
  }
  reduce_kernel<<<1, 64, 0, stream>>>(la_ws, out);
}